// Round 5
// baseline (3569.936 us; speedup 1.0000x reference)
//
#include <hip/hip_runtime.h>

#define NPTS   8192
#define CCH    32
#define LDIM   64
#define ODIM   128
#define KNN    16
#define TILEC  128                 // candidates per LDS tile
#define NTIL   (NPTS / TILEC)      // 64
#define QPB    16                  // queries per block (4 waves x 4)
#define NBLK   ((4 * NPTS) / QPB)  // 2048 blocks

typedef const __attribute__((address_space(1))) void* gas_ptr;
typedef __attribute__((address_space(3))) void* las_ptr;

// Prologue: squared norms of all 32768 points into d_ws.
__global__ void sq_kernel(const float* __restrict__ x, float* __restrict__ sqg) {
    int i = blockIdx.x * 256 + threadIdx.x;
    const float4* p = (const float4*)(x + (size_t)i * CCH);
    float s = 0.f;
    #pragma unroll
    for (int k = 0; k < 8; ++k) {
        float4 v = p[k];
        s += v.x * v.x + v.y * v.y + v.z * v.z + v.w * v.w;
    }
    sqg[i] = s;
}

// LDS: bufA @0 (16 KB), bufB @16384 (16 KB), sqsA @32768 (512 B), sqsB @33280 (512 B)
// epilogue overlay @0: kn (1 KB), pl 16*33 f, hh 16*65 f
#define LDS_BYTES 33792
__global__ __launch_bounds__(256, 4)
void graph_layer_kernel(const float* __restrict__ x,
                        const float* __restrict__ sqg,
                        const float* __restrict__ Wl,
                        const float* __restrict__ bl,
                        const float* __restrict__ Wc,
                        const float* __restrict__ bc,
                        float* __restrict__ out)
{
    __shared__ __align__(16) char smem[LDS_BYTES];
    char*  bufA = smem;
    char*  bufB = smem + 16384;
    float* sqsA = (float*)(smem + 32768);
    float* sqsB = (float*)(smem + 33280);
    int*   kn   = (int*)smem;                 // [16][16]
    float* pl   = (float*)(smem + 1024);      // [16][33]
    float* hh   = (float*)(smem + 3136);      // [16][65]

    const int tid  = threadIdx.x;
    const int lane = tid & 63;
    const int w    = tid >> 6;
    const float INF = __builtin_inff();

    const int qb0 = blockIdx.x * QPB;
    const int b   = qb0 >> 13;
    const float* xb  = x   + (size_t)(b << 13) * CCH;
    const float* sqb = sqg + (b << 13);

    // wave-uniform query base -> scalar-pipe (s_load) query fetches in the k-loop
    const int qrow = __builtin_amdgcn_readfirstlane(qb0 + w * 4);
    const float4* qp = (const float4*)(x + (size_t)qrow * CCH);  // 4 queries, 32 float4

    // distributed sorted-16: query g's list lives in lanes g*16..g*16+15
    float selk = INF;
    int   seli = 0;
    float T0 = INF, T1 = INF, T2 = INF, T3 = INF;

    auto stage = [&](int T, char* bf, float* sqs) {
        // 1024 x 16B chunks, 4 per thread; layout chunk-major: slot k*128+c
        #pragma unroll
        for (int i = 0; i < 4; ++i) {
            int chunk = tid + i * 256;
            int k = chunk >> 7, c = chunk & 127;
            const float* gsrc = xb + (size_t)(T * TILEC + c) * CCH + k * 4;
            __builtin_amdgcn_global_load_lds((gas_ptr)gsrc,
                                             (las_ptr)(bf + (size_t)chunk * 16), 16, 0, 0);
        }
        if (tid < TILEC)
            __builtin_amdgcn_global_load_lds((gas_ptr)(sqb + T * TILEC + tid),
                                             (las_ptr)(sqs + tid), 4, 0, 0);
    };

    auto sel_insert = [&](float key, float& Tref, int gsel, int cbase) {
        unsigned long long m = __ballot(key < Tref);
        if (m) {
            const bool ing = (lane >> 4) == gsel;
            do {
                int src = __ffsll(m) - 1;          // ascending lane = ascending idx
                float nk = __shfl(key, src);
                int   ni = cbase + src;
                float upk = __shfl_up(selk, 1);
                int   upi = __shfl_up(seli, 1);
                bool pme   = nk < selk;            // strict <: lower idx wins ties
                bool pprev = (nk < upk) && ((lane & 15) != 0);
                float rk = pme ? (pprev ? upk : nk) : selk;
                int   ri = pme ? (pprev ? upi : ni) : seli;
                if (ing) { selk = rk; seli = ri; }
                m &= (m - 1);
            } while (m);
            Tref = __shfl(selk, gsel * 16 + 15);   // new 16th-best threshold
        }
    };

    // ---- scan all 8192 candidates, double-buffered DMA tiles ----
    stage(0, bufA, sqsA);
    __syncthreads();
    #pragma unroll 1
    for (int T = 0; T < NTIL; ++T) {
        const bool cur = T & 1;
        if (T + 1 < NTIL) stage(T + 1, cur ? bufA : bufB, cur ? sqsA : sqsB);
        const float4* cb = (const float4*)(cur ? bufB : bufA);
        const float*  sv = cur ? sqsB : sqsA;
        #pragma unroll 1
        for (int s = 0; s < 2; ++s) {
            const int cl = s * 64 + lane;
            float a0 = 0.f, a1 = 0.f, a2 = 0.f, a3 = 0.f;
            #pragma unroll
            for (int k = 0; k < 8; ++k) {
                float4 cv = cb[k * TILEC + cl];    // 16B lane stride: conflict-free
                float4 qa = qp[k], qb2 = qp[8 + k], qc = qp[16 + k], qd = qp[24 + k];
                a0 = fmaf(cv.x, qa.x, a0);  a0 = fmaf(cv.y, qa.y, a0);
                a0 = fmaf(cv.z, qa.z, a0);  a0 = fmaf(cv.w, qa.w, a0);
                a1 = fmaf(cv.x, qb2.x, a1); a1 = fmaf(cv.y, qb2.y, a1);
                a1 = fmaf(cv.z, qb2.z, a1); a1 = fmaf(cv.w, qb2.w, a1);
                a2 = fmaf(cv.x, qc.x, a2);  a2 = fmaf(cv.y, qc.y, a2);
                a2 = fmaf(cv.z, qc.z, a2);  a2 = fmaf(cv.w, qc.w, a2);
                a3 = fmaf(cv.x, qd.x, a3);  a3 = fmaf(cv.y, qd.y, a3);
                a3 = fmaf(cv.z, qd.z, a3);  a3 = fmaf(cv.w, qd.w, a3);
            }
            const float sqv = sv[cl];
            float k0 = fmaf(-2.f, a0, sqv);
            float k1 = fmaf(-2.f, a1, sqv);
            float k2 = fmaf(-2.f, a2, sqv);
            float k3 = fmaf(-2.f, a3, sqv);
            const int cbase = T * TILEC + s * 64;
            sel_insert(k0, T0, 0, cbase);
            sel_insert(k1, T1, 1, cbase);
            sel_insert(k2, T2, 2, cbase);
            sel_insert(k3, T3, 3, cbase);
        }
        __syncthreads();
    }

    // ---- write knn indices (each lane holds exactly one (query, rank)) ----
    kn[(w * 4 + (lane >> 4)) * KNN + (lane & 15)] = seli;
    __syncthreads();

    // ---- gather + max-pool: thread -> (q = tid>>4, channels 2*(tid&15)) ----
    {
        int q = tid >> 4, c2 = (tid & 15) * 2;
        float m0 = -INF, m1 = -INF;
        #pragma unroll
        for (int k = 0; k < KNN; ++k) {
            int j = kn[q * KNN + k];
            float2 v = *(const float2*)(xb + (size_t)j * CCH + c2);
            m0 = fmaxf(m0, v.x); m1 = fmaxf(m1, v.y);
        }
        pl[q * 33 + c2] = m0; pl[q * 33 + c2 + 1] = m1;
    }
    __syncthreads();

    // ---- linear 32->64 ----
    {
        int l = tid & 63, qg = tid >> 6;
        #pragma unroll 1
        for (int q = qg; q < QPB; q += 4) {
            float acc = bl[l];
            #pragma unroll
            for (int c = 0; c < CCH; ++c)
                acc = fmaf(pl[q * 33 + c], Wl[c * LDIM + l], acc);
            hh[q * 65 + l] = acc;
        }
    }
    __syncthreads();

    // ---- conv1x1 64->128 + relu ----
    {
        int o = tid & 127, qh = tid >> 7;
        #pragma unroll 1
        for (int q = qh; q < QPB; q += 2) {
            float acc = bc[o];
            #pragma unroll
            for (int l = 0; l < LDIM; ++l)
                acc = fmaf(hh[q * 65 + l], Wc[l * ODIM + o], acc);
            out[(size_t)(qb0 + q) * ODIM + o] = fmaxf(acc, 0.f);
        }
    }
}

extern "C" void kernel_launch(void* const* d_in, const int* in_sizes, int n_in,
                              void* d_out, int out_size, void* d_ws, size_t ws_size,
                              hipStream_t stream) {
    const float* x  = (const float*)d_in[0];
    const float* Wl = (const float*)d_in[1];
    const float* bl = (const float*)d_in[2];
    const float* Wc = (const float*)d_in[3];
    const float* bc = (const float*)d_in[4];
    float* out = (float*)d_out;
    float* sqf = (float*)d_ws;                 // 32768 floats = 128 KB
    (void)in_sizes; (void)n_in; (void)out_size; (void)ws_size;

    hipLaunchKernelGGL(sq_kernel, dim3((4 * NPTS) / 256), dim3(256), 0, stream, x, sqf);
    hipLaunchKernelGGL(graph_layer_kernel, dim3(NBLK), dim3(256), 0, stream,
                       x, sqf, Wl, bl, Wc, bc, out);
}

// Round 6
// 1314.967 us; speedup vs baseline: 2.7148x; 2.7148x over previous
//
#include <hip/hip_runtime.h>

#define NPTS   8192
#define CCH    32
#define LDIM   64
#define ODIM   128
#define KNN    16
#define TILEC  128                 // candidates per LDS tile
#define NTIL   (NPTS / TILEC)      // 64
#define QPB    16                  // queries per block (4 waves x 4)
#define NBLK   ((4 * NPTS) / QPB)  // 2048 blocks

typedef const __attribute__((address_space(1))) void* gas_ptr;
typedef __attribute__((address_space(3))) void* las_ptr;

// Prologue: squared norms of all 32768 points into d_ws.
__global__ void sq_kernel(const float* __restrict__ x, float* __restrict__ sqg) {
    int i = blockIdx.x * 256 + threadIdx.x;
    const float4* p = (const float4*)(x + (size_t)i * CCH);
    float s = 0.f;
    #pragma unroll
    for (int k = 0; k < 8; ++k) {
        float4 v = p[k];
        s += v.x * v.x + v.y * v.y + v.z * v.z + v.w * v.w;
    }
    sqg[i] = s;
}

// LDS: bufA @0 (16 KB), bufB @16384 (16 KB), sqsA @32768 (512 B), sqsB @33280 (512 B)
// epilogue overlay @0: kn (1 KB), pl 16*33 f @1024, hh 16*65 f @3136
#define LDS_BYTES 33792
__global__ __launch_bounds__(256, 3)
void graph_layer_kernel(const float* __restrict__ x,
                        const float* __restrict__ sqg,
                        const float* __restrict__ Wl,
                        const float* __restrict__ bl,
                        const float* __restrict__ Wc,
                        const float* __restrict__ bc,
                        float* __restrict__ out)
{
    __shared__ __align__(16) char smem[LDS_BYTES];
    char*  bufA = smem;
    char*  bufB = smem + 16384;
    float* sqsA = (float*)(smem + 32768);
    float* sqsB = (float*)(smem + 33280);
    int*   kn   = (int*)smem;                 // [16][16]
    float* pl   = (float*)(smem + 1024);      // [16][33]
    float* hh   = (float*)(smem + 3136);      // [16][65]

    const int tid  = threadIdx.x;
    const int lane = tid & 63;
    const int w    = tid >> 6;
    const float INF = __builtin_inff();

    const int qb0 = blockIdx.x * QPB;
    const int b   = qb0 >> 13;
    const float* xb  = x   + (size_t)(b << 13) * CCH;
    const float* sqb = sqg + (b << 13);

    // ---- load this wave's 4 queries ONCE and PIN them in VGPRs ----
    // (r3/r5 failure mode: compiler remat'd / spilled these. The asm barrier
    //  makes the values opaque: no remat, and spilling 128 regs would be a
    //  visible catastrophe the allocator avoids at 170-reg budget.)
    float q[4][32];
    {
        const float4* qp = (const float4*)(x + (size_t)(qb0 + w * 4) * CCH);
        #pragma unroll
        for (int g = 0; g < 4; ++g)
            #pragma unroll
            for (int k = 0; k < 8; ++k) {
                float4 v = qp[g * 8 + k];
                q[g][k * 4 + 0] = v.x; q[g][k * 4 + 1] = v.y;
                q[g][k * 4 + 2] = v.z; q[g][k * 4 + 3] = v.w;
            }
        #pragma unroll
        for (int i = 0; i < 32; ++i)
            asm volatile("" : "+v"(q[0][i]), "+v"(q[1][i]), "+v"(q[2][i]), "+v"(q[3][i]));
    }

    // distributed sorted-16: query g's list lives in lanes g*16..g*16+15
    float selk = INF;
    int   seli = 0;
    float T0 = INF, T1 = INF, T2 = INF, T3 = INF;

    auto stage = [&](int T, char* bf, float* sqs) {
        // 1024 x 16B chunks, 4 per thread; chunk-major layout: slot k*128+c
        #pragma unroll
        for (int i = 0; i < 4; ++i) {
            int chunk = tid + i * 256;
            int k = chunk >> 7, c = chunk & 127;
            const float* gsrc = xb + (size_t)(T * TILEC + c) * CCH + k * 4;
            __builtin_amdgcn_global_load_lds((gas_ptr)gsrc,
                                             (las_ptr)(bf + (size_t)chunk * 16), 16, 0, 0);
        }
        if (tid < TILEC)
            __builtin_amdgcn_global_load_lds((gas_ptr)(sqb + T * TILEC + tid),
                                             (las_ptr)(sqs + tid), 4, 0, 0);
    };

    auto sel_insert = [&](float key, float& Tref, int gsel, int cbase) {
        unsigned long long m = __ballot(key < Tref);
        if (m) {
            const bool ing = (lane >> 4) == gsel;
            do {
                int src = __ffsll(m) - 1;          // ascending lane = ascending idx
                float nk = __shfl(key, src);
                int   ni = cbase + src;
                float upk = __shfl_up(selk, 1);
                int   upi = __shfl_up(seli, 1);
                bool pme   = nk < selk;            // strict <: lower idx wins ties
                bool pprev = (nk < upk) && ((lane & 15) != 0);
                float rk = pme ? (pprev ? upk : nk) : selk;
                int   ri = pme ? (pprev ? upi : ni) : seli;
                if (ing) { selk = rk; seli = ri; }
                m &= (m - 1);
            } while (m);
            Tref = __shfl(selk, gsel * 16 + 15);   // new 16th-best threshold
        }
    };

    // ---- scan all 8192 candidates, double-buffered DMA tiles ----
    stage(0, bufA, sqsA);
    __syncthreads();
    #pragma unroll 1
    for (int T = 0; T < NTIL; ++T) {
        const bool cur = T & 1;
        if (T + 1 < NTIL) stage(T + 1, cur ? bufA : bufB, cur ? sqsA : sqsB);
        const float4* cb = (const float4*)(cur ? bufB : bufA);
        const float*  sv = cur ? sqsB : sqsA;
        #pragma unroll 1
        for (int s = 0; s < 2; ++s) {
            const int cl = s * 64 + lane;
            float a0 = 0.f, a1 = 0.f, a2 = 0.f, a3 = 0.f;
            #pragma unroll
            for (int k = 0; k < 8; ++k) {
                float4 cv = cb[k * TILEC + cl];    // 16B lane stride: conflict-free
                a0 = fmaf(cv.x, q[0][k*4+0], a0); a0 = fmaf(cv.y, q[0][k*4+1], a0);
                a0 = fmaf(cv.z, q[0][k*4+2], a0); a0 = fmaf(cv.w, q[0][k*4+3], a0);
                a1 = fmaf(cv.x, q[1][k*4+0], a1); a1 = fmaf(cv.y, q[1][k*4+1], a1);
                a1 = fmaf(cv.z, q[1][k*4+2], a1); a1 = fmaf(cv.w, q[1][k*4+3], a1);
                a2 = fmaf(cv.x, q[2][k*4+0], a2); a2 = fmaf(cv.y, q[2][k*4+1], a2);
                a2 = fmaf(cv.z, q[2][k*4+2], a2); a2 = fmaf(cv.w, q[2][k*4+3], a2);
                a3 = fmaf(cv.x, q[3][k*4+0], a3); a3 = fmaf(cv.y, q[3][k*4+1], a3);
                a3 = fmaf(cv.z, q[3][k*4+2], a3); a3 = fmaf(cv.w, q[3][k*4+3], a3);
            }
            const float sqv = sv[cl];
            float k0 = fmaf(-2.f, a0, sqv);
            float k1 = fmaf(-2.f, a1, sqv);
            float k2 = fmaf(-2.f, a2, sqv);
            float k3 = fmaf(-2.f, a3, sqv);
            const int cbase = T * TILEC + s * 64;
            sel_insert(k0, T0, 0, cbase);
            sel_insert(k1, T1, 1, cbase);
            sel_insert(k2, T2, 2, cbase);
            sel_insert(k3, T3, 3, cbase);
        }
        __syncthreads();
    }

    // ---- write knn indices (each lane holds exactly one (query, rank)) ----
    kn[(w * 4 + (lane >> 4)) * KNN + (lane & 15)] = seli;
    __syncthreads();

    // ---- gather + max-pool: thread -> (q = tid>>4, channels 2*(tid&15)) ----
    {
        int qq = tid >> 4, c2 = (tid & 15) * 2;
        float m0 = -INF, m1 = -INF;
        #pragma unroll
        for (int k = 0; k < KNN; ++k) {
            int j = kn[qq * KNN + k];
            float2 v = *(const float2*)(xb + (size_t)j * CCH + c2);
            m0 = fmaxf(m0, v.x); m1 = fmaxf(m1, v.y);
        }
        pl[qq * 33 + c2] = m0; pl[qq * 33 + c2 + 1] = m1;
    }
    __syncthreads();

    // ---- linear 32->64 ----
    {
        int l = tid & 63, qg = tid >> 6;
        #pragma unroll 1
        for (int qq = qg; qq < QPB; qq += 4) {
            float acc = bl[l];
            #pragma unroll
            for (int c = 0; c < CCH; ++c)
                acc = fmaf(pl[qq * 33 + c], Wl[c * LDIM + l], acc);
            hh[qq * 65 + l] = acc;
        }
    }
    __syncthreads();

    // ---- conv1x1 64->128 + relu ----
    {
        int o = tid & 127, qh = tid >> 7;
        #pragma unroll 1
        for (int qq = qh; qq < QPB; qq += 2) {
            float acc = bc[o];
            #pragma unroll
            for (int l = 0; l < LDIM; ++l)
                acc = fmaf(hh[qq * 65 + l], Wc[l * ODIM + o], acc);
            out[(size_t)(qb0 + qq) * ODIM + o] = fmaxf(acc, 0.f);
        }
    }
}

extern "C" void kernel_launch(void* const* d_in, const int* in_sizes, int n_in,
                              void* d_out, int out_size, void* d_ws, size_t ws_size,
                              hipStream_t stream) {
    const float* x  = (const float*)d_in[0];
    const float* Wl = (const float*)d_in[1];
    const float* bl = (const float*)d_in[2];
    const float* Wc = (const float*)d_in[3];
    const float* bc = (const float*)d_in[4];
    float* out = (float*)d_out;
    float* sqf = (float*)d_ws;                 // 32768 floats = 128 KB
    (void)in_sizes; (void)n_in; (void)out_size; (void)ws_size;

    hipLaunchKernelGGL(sq_kernel, dim3((4 * NPTS) / 256), dim3(256), 0, stream, x, sqf);
    hipLaunchKernelGGL(graph_layer_kernel, dim3(NBLK), dim3(256), 0, stream,
                       x, sqf, Wl, bl, Wc, bc, out);
}

// Round 7
// 527.889 us; speedup vs baseline: 6.7627x; 2.4910x over previous
//
#include <hip/hip_runtime.h>

#define NPTS   8192
#define CCH    32
#define LDIM   64
#define ODIM   128
#define KNN    16
#define TILEC  128                 // candidates per LDS tile
#define NTIL   (NPTS / TILEC)      // 64
#define QPB    16                  // queries per block (4 waves x 4)
#define NBLK   ((4 * NPTS) / QPB)  // 2048 blocks

typedef const __attribute__((address_space(1))) void* gas_ptr;
typedef __attribute__((address_space(3))) void* las_ptr;
typedef float vf16 __attribute__((ext_vector_type(16)));

// Prologue: squared norms of all 32768 points into d_ws.
__global__ void sq_kernel(const float* __restrict__ x, float* __restrict__ sqg) {
    int i = blockIdx.x * 256 + threadIdx.x;
    const float4* p = (const float4*)(x + (size_t)i * CCH);
    float s = 0.f;
    #pragma unroll
    for (int k = 0; k < 8; ++k) {
        float4 v = p[k];
        s += v.x * v.x + v.y * v.y + v.z * v.z + v.w * v.w;
    }
    sqg[i] = s;
}

__device__ __forceinline__ float dpp_shr1_f(float v) {
    int i = __float_as_int(v);
    return __int_as_float(__builtin_amdgcn_update_dpp(i, i, 0x111, 0xf, 0xf, false));
}
__device__ __forceinline__ int dpp_shr1_i(int v) {
    return __builtin_amdgcn_update_dpp(v, v, 0x111, 0xf, 0xf, false);
}
__device__ __forceinline__ float readlane_f(float v, int l) {
    return __int_as_float(__builtin_amdgcn_readlane(__float_as_int(v), l));
}

// LDS: bufA @0 (16 KB), bufB @16384 (16 KB), sqsA @32768 (512 B), sqsB @33280 (512 B)
// epilogue overlay @0: kn (1 KB), pl 16*33 f @1024, hh 16*65 f @3136
#define LDS_BYTES 33792
__global__ __launch_bounds__(256, 4)
void graph_layer_kernel(const float* __restrict__ x,
                        const float* __restrict__ sqg,
                        const float* __restrict__ Wl,
                        const float* __restrict__ bl,
                        const float* __restrict__ Wc,
                        const float* __restrict__ bc,
                        float* __restrict__ out)
{
    __shared__ __align__(16) char smem[LDS_BYTES];
    char*  bufA = smem;
    char*  bufB = smem + 16384;
    float* sqsA = (float*)(smem + 32768);
    float* sqsB = (float*)(smem + 33280);
    int*   kn   = (int*)smem;                 // [16][16]
    float* pl   = (float*)(smem + 1024);      // [16][33]
    float* hh   = (float*)(smem + 3136);      // [16][65]

    const int tid  = threadIdx.x;
    const int lane = tid & 63;
    const int w    = tid >> 6;
    const float INF = __builtin_inff();

    const int qb0 = blockIdx.x * QPB;
    const int b   = qb0 >> 13;
    const float* xb  = x   + (size_t)(b << 13) * CCH;
    const float* sqb = sqg + (b << 13);

    // ---- queries 0,1 of this wave -> SGPRs (64 regs, zero VGPR cost) ----
    const int qrow = __builtin_amdgcn_readfirstlane(qb0 + w * 4);
    const float* qp = x + (size_t)qrow * CCH;
    vf16 qsa0, qsa1, qsb0, qsb1;
    asm volatile(
        "s_load_dwordx16 %0, %4, 0x0\n\t"
        "s_load_dwordx16 %1, %4, 0x40\n\t"
        "s_load_dwordx16 %2, %4, 0x80\n\t"
        "s_load_dwordx16 %3, %4, 0xc0\n\t"
        "s_waitcnt lgkmcnt(0)"
        : "=s"(qsa0), "=s"(qsa1), "=s"(qsb0), "=s"(qsb1)
        : "s"(qp));

    // ---- queries 2,3 -> VGPRs (64 floats; fits under the 128 cap) ----
    float qv[2][32];
    {
        const float4* q2p = (const float4*)(x + (size_t)(qrow + 2) * CCH);
        #pragma unroll
        for (int g = 0; g < 2; ++g)
            #pragma unroll
            for (int k = 0; k < 8; ++k) {
                float4 v = q2p[g * 8 + k];
                qv[g][k * 4 + 0] = v.x; qv[g][k * 4 + 1] = v.y;
                qv[g][k * 4 + 2] = v.z; qv[g][k * 4 + 3] = v.w;
            }
        #pragma unroll
        for (int i = 0; i < 32; ++i)
            asm volatile("" : "+v"(qv[0][i]), "+v"(qv[1][i]));
    }

    // distributed sorted-16: query g's list lives in lanes g*16..g*16+15
    float selk = INF;
    int   seli = 0;
    float T0 = INF, T1 = INF, T2 = INF, T3 = INF;

    auto stage = [&](int T, char* bf, float* sqs) {
        #pragma unroll
        for (int i = 0; i < 4; ++i) {
            int chunk = tid + i * 256;
            int k = chunk >> 7, c = chunk & 127;
            const float* gsrc = xb + (size_t)(T * TILEC + c) * CCH + k * 4;
            __builtin_amdgcn_global_load_lds((gas_ptr)gsrc,
                                             (las_ptr)(bf + (size_t)chunk * 16), 16, 0, 0);
        }
        if (tid < TILEC)
            __builtin_amdgcn_global_load_lds((gas_ptr)(sqb + T * TILEC + tid),
                                             (las_ptr)(sqs + tid), 4, 0, 0);
    };

    // pure-VALU insert: readlane + DPP row_shr:1 (16-lane segments = DPP rows)
    auto sel_insert = [&](float key, float Tr, int gsel, int cbase) -> float {
        unsigned long long m = __ballot(key < Tr);
        if (m) {
            const bool ing = (lane >> 4) == gsel;
            do {
                int src = __ffsll(m) - 1;          // ascending lane = ascending idx
                float nk = readlane_f(key, src);
                int   ni = cbase + src;
                float upk = dpp_shr1_f(selk);
                int   upi = dpp_shr1_i(seli);
                bool pme   = nk < selk;            // strict <: lower idx wins ties
                bool pprev = (nk < upk) && ((lane & 15) != 0);
                float rk = pme ? (pprev ? upk : nk) : selk;
                int   ri = pme ? (pprev ? upi : ni) : seli;
                if (ing) { selk = rk; seli = ri; }
                m &= (m - 1);
            } while (m);
            Tr = readlane_f(selk, gsel * 16 + 15); // new 16th-best threshold
        }
        return Tr;
    };

    // ---- scan all 8192 candidates, double-buffered DMA tiles ----
    stage(0, bufA, sqsA);
    __syncthreads();
    #pragma unroll 1
    for (int T = 0; T < NTIL; ++T) {
        const bool cur = T & 1;
        if (T + 1 < NTIL) stage(T + 1, cur ? bufA : bufB, cur ? sqsA : sqsB);
        const float4* cb = (const float4*)(cur ? bufB : bufA);
        const float*  sv = cur ? sqsB : sqsA;
        #pragma unroll 1
        for (int s = 0; s < 2; ++s) {
            const int cl = s * 64 + lane;
            float a0 = 0.f, a1 = 0.f, a2 = 0.f, a3 = 0.f;
            #pragma unroll
            for (int k = 0; k < 8; ++k) {
                float4 cv = cb[k * TILEC + cl];    // 16B lane stride: conflict-free
                // query 0 (SGPR): elems k*4..k*4+3 from qsa0/qsa1
                a0 = fmaf(cv.x, (k < 4 ? qsa0[(k&3)*4+0] : qsa1[(k&3)*4+0]), a0);
                a0 = fmaf(cv.y, (k < 4 ? qsa0[(k&3)*4+1] : qsa1[(k&3)*4+1]), a0);
                a0 = fmaf(cv.z, (k < 4 ? qsa0[(k&3)*4+2] : qsa1[(k&3)*4+2]), a0);
                a0 = fmaf(cv.w, (k < 4 ? qsa0[(k&3)*4+3] : qsa1[(k&3)*4+3]), a0);
                // query 1 (SGPR)
                a1 = fmaf(cv.x, (k < 4 ? qsb0[(k&3)*4+0] : qsb1[(k&3)*4+0]), a1);
                a1 = fmaf(cv.y, (k < 4 ? qsb0[(k&3)*4+1] : qsb1[(k&3)*4+1]), a1);
                a1 = fmaf(cv.z, (k < 4 ? qsb0[(k&3)*4+2] : qsb1[(k&3)*4+2]), a1);
                a1 = fmaf(cv.w, (k < 4 ? qsb0[(k&3)*4+3] : qsb1[(k&3)*4+3]), a1);
                // queries 2,3 (VGPR)
                a2 = fmaf(cv.x, qv[0][k*4+0], a2); a2 = fmaf(cv.y, qv[0][k*4+1], a2);
                a2 = fmaf(cv.z, qv[0][k*4+2], a2); a2 = fmaf(cv.w, qv[0][k*4+3], a2);
                a3 = fmaf(cv.x, qv[1][k*4+0], a3); a3 = fmaf(cv.y, qv[1][k*4+1], a3);
                a3 = fmaf(cv.z, qv[1][k*4+2], a3); a3 = fmaf(cv.w, qv[1][k*4+3], a3);
            }
            const float sqv = sv[cl];
            float k0 = fmaf(-2.f, a0, sqv);
            float k1 = fmaf(-2.f, a1, sqv);
            float k2 = fmaf(-2.f, a2, sqv);
            float k3 = fmaf(-2.f, a3, sqv);
            const int cbase = T * TILEC + s * 64;
            T0 = sel_insert(k0, T0, 0, cbase);
            T1 = sel_insert(k1, T1, 1, cbase);
            T2 = sel_insert(k2, T2, 2, cbase);
            T3 = sel_insert(k3, T3, 3, cbase);
        }
        __syncthreads();
    }

    // ---- write knn indices (each lane holds exactly one (query, rank)) ----
    kn[(w * 4 + (lane >> 4)) * KNN + (lane & 15)] = seli;
    __syncthreads();

    // ---- gather + max-pool: thread -> (q = tid>>4, channels 2*(tid&15)) ----
    {
        int qq = tid >> 4, c2 = (tid & 15) * 2;
        float m0 = -INF, m1 = -INF;
        #pragma unroll
        for (int k = 0; k < KNN; ++k) {
            int j = kn[qq * KNN + k];
            float2 v = *(const float2*)(xb + (size_t)j * CCH + c2);
            m0 = fmaxf(m0, v.x); m1 = fmaxf(m1, v.y);
        }
        pl[qq * 33 + c2] = m0; pl[qq * 33 + c2 + 1] = m1;
    }
    __syncthreads();

    // ---- linear 32->64 ----
    {
        int l = tid & 63, qg = tid >> 6;
        #pragma unroll 1
        for (int qq = qg; qq < QPB; qq += 4) {
            float acc = bl[l];
            #pragma unroll
            for (int c = 0; c < CCH; ++c)
                acc = fmaf(pl[qq * 33 + c], Wl[c * LDIM + l], acc);
            hh[qq * 65 + l] = acc;
        }
    }
    __syncthreads();

    // ---- conv1x1 64->128 + relu ----
    {
        int o = tid & 127, qh = tid >> 7;
        #pragma unroll 1
        for (int qq = qh; qq < QPB; qq += 2) {
            float acc = bc[o];
            #pragma unroll
            for (int l = 0; l < LDIM; ++l)
                acc = fmaf(hh[qq * 65 + l], Wc[l * ODIM + o], acc);
            out[(size_t)(qb0 + qq) * ODIM + o] = fmaxf(acc, 0.f);
        }
    }
}

extern "C" void kernel_launch(void* const* d_in, const int* in_sizes, int n_in,
                              void* d_out, int out_size, void* d_ws, size_t ws_size,
                              hipStream_t stream) {
    const float* x  = (const float*)d_in[0];
    const float* Wl = (const float*)d_in[1];
    const float* bl = (const float*)d_in[2];
    const float* Wc = (const float*)d_in[3];
    const float* bc = (const float*)d_in[4];
    float* out = (float*)d_out;
    float* sqf = (float*)d_ws;                 // 32768 floats = 128 KB
    (void)in_sizes; (void)n_in; (void)out_size; (void)ws_size;

    hipLaunchKernelGGL(sq_kernel, dim3((4 * NPTS) / 256), dim3(256), 0, stream, x, sqf);
    hipLaunchKernelGGL(graph_layer_kernel, dim3(NBLK), dim3(256), 0, stream,
                       x, sqf, Wl, bl, Wc, bc, out);
}

// Round 8
// 525.941 us; speedup vs baseline: 6.7877x; 1.0037x over previous
//
#include <hip/hip_runtime.h>

#define NPTS   8192
#define CCH    32
#define LDIM   64
#define ODIM   128
#define KNN    16
#define QPB    64                  // queries per block (16 per wave, MFMA tile rows)
#define TILEC  128                 // candidates per LDS tile
#define NTIL   (NPTS / TILEC)      // 64
#define NBLK   ((4 * NPTS) / QPB)  // 512 blocks -- all co-resident
#define SCAP   48                  // survivor capacity per query
#define CSTRIDE 80                 // bytes per candidate row in LDS (32 fp16 + pad, 16B-aligned)
#define EPS_MARGIN 0.75f           // >= 2*eps bound for fp16 distance error

typedef _Float16 half8  __attribute__((ext_vector_type(8)));
typedef _Float16 half4v __attribute__((ext_vector_type(4)));
typedef float    float4v __attribute__((ext_vector_type(4)));

// Prologue: squared norms of all 32768 points into d_ws (exact fp32).
__global__ void sq_kernel(const float* __restrict__ x, float* __restrict__ sqg) {
    int i = blockIdx.x * 256 + threadIdx.x;
    const float4* p = (const float4*)(x + (size_t)i * CCH);
    float s = 0.f;
    #pragma unroll
    for (int k = 0; k < 8; ++k) {
        float4 v = p[k];
        s += v.x * v.x + v.y * v.y + v.z * v.z + v.w * v.w;
    }
    sqg[i] = s;
}

__device__ __forceinline__ float readlane_f(float v, int l) {
    return __int_as_float(__builtin_amdgcn_readlane(__float_as_int(v), l));
}
__device__ __forceinline__ float dpp_shr1_f(float v) {
    int i = __float_as_int(v);
    return __int_as_float(__builtin_amdgcn_update_dpp(i, i, 0x111, 0xf, 0xf, false));
}
// broadcast lane 15 of each 16-lane row to the whole row (BitMode: and=0x10,or=0x0F)
__device__ __forceinline__ float bcast15_f(float v) {
    return __int_as_float(__builtin_amdgcn_ds_swizzle(__float_as_int(v), 0x01F0));
}

// LDS: stream0 @0 (10240), stream1 @10240, sqs0 @20480 (512), sqs1 @20992 (512),
//      slist @21504 (64*48*4=12288), skeys @33792 (12288), scnt @46080 (256)  -> 46336 B
// epilogue overlay: kn @0 (4096), pl @4096 (64*33*4=8448), hh @12544 (64*65*4=16640)
#define LDS_BYTES 46336
__global__ __launch_bounds__(256, 2)
void graph_layer_kernel(const float* __restrict__ x,
                        const float* __restrict__ sqg,
                        const float* __restrict__ Wl,
                        const float* __restrict__ bl,
                        const float* __restrict__ Wc,
                        const float* __restrict__ bc,
                        float* __restrict__ out)
{
    __shared__ __align__(16) char smem[LDS_BYTES];
    char*  stream0 = smem;
    char*  stream1 = smem + 10240;
    float* sqs0    = (float*)(smem + 20480);
    float* sqs1    = (float*)(smem + 20992);
    int*   slist   = (int*)(smem + 21504);
    float* skeys   = (float*)(smem + 33792);
    int*   scnt    = (int*)(smem + 46080);
    int*   kn      = (int*)smem;               // epilogue overlays
    float* pl      = (float*)(smem + 4096);
    float* hh      = (float*)(smem + 12544);

    const int tid  = threadIdx.x;
    const int lane = tid & 63;
    const int w    = tid >> 6;
    const float INF = __builtin_inff();

    const int qb0 = blockIdx.x * QPB;          // global query base (one batch: 8192%64==0)
    const int b   = qb0 >> 13;
    const int qbl = qb0 & (NPTS - 1);          // batch-local query base
    const float* xb  = x   + (size_t)(b << 13) * CCH;
    const float* sqb = sqg + (b << 13);

    // ---- A-fragment: wave's 16 queries in fp16 (4 VGPRs total) ----
    // A[m=lane&15][k=(lane>>4)*8 + j]
    half8 qh;
    {
        int m = lane & 15, quad = lane >> 4;
        const float* qr = x + (size_t)(qb0 + w * 16 + m) * CCH + quad * 8;
        float4 f0 = *(const float4*)qr;
        float4 f1 = *(const float4*)(qr + 4);
        qh[0] = (_Float16)f0.x; qh[1] = (_Float16)f0.y;
        qh[2] = (_Float16)f0.z; qh[3] = (_Float16)f0.w;
        qh[4] = (_Float16)f1.x; qh[5] = (_Float16)f1.y;
        qh[6] = (_Float16)f1.z; qh[7] = (_Float16)f1.w;
    }

    // staging: thread handles 4 global float4 chunks -> fp16 LDS rows
    float4 r0, r1, r2, r3; float sqv = 0.f;
    auto stage_load = [&](int T) {
        const float4* g = (const float4*)(xb + (size_t)T * TILEC * CCH);
        r0 = g[tid]; r1 = g[tid + 256]; r2 = g[tid + 512]; r3 = g[tid + 768];
        if (tid < TILEC) sqv = sqb[T * TILEC + tid];
    };
    auto stage_write = [&](char* buf, float* sqs) {
        auto wr = [&](int ch, float4 r) {
            int cd = ch >> 3, kq = ch & 7;
            half4v h;
            h[0] = (_Float16)r.x; h[1] = (_Float16)r.y;
            h[2] = (_Float16)r.z; h[3] = (_Float16)r.w;
            *(half4v*)(buf + cd * CSTRIDE + kq * 8) = h;
        };
        wr(tid, r0); wr(tid + 256, r1); wr(tid + 512, r2); wr(tid + 768, r3);
        if (tid < TILEC) sqs[tid] = sqv;
    };

    // per-lane state: 4 distributed sorted-16 value lists (query 4*(lane>>4)+j at reg j)
    float selk[4] = {INF, INF, INF, INF};
    float Tth[4]  = {INF, INF, INF, INF};

    // ================= PASS 1: approx scan -> per-query 16th-best value ==========
    stage_load(0); stage_write(stream0, sqs0);
    __syncthreads();
    #pragma unroll 1
    for (int T = 0; T < NTIL; ++T) {
        stage_load((T + 1 < NTIL) ? T + 1 : T);
        const char*  cb = (T & 1) ? stream1 : stream0;
        const float* sv = (T & 1) ? sqs1 : sqs0;
        #pragma unroll
        for (int st = 0; st < 8; ++st) {
            half8 bh = *(const half8*)(cb + (size_t)(st * 16 + (lane & 15)) * CSTRIDE
                                          + (lane >> 4) * 16);
            float sc = sv[st * 16 + (lane & 15)];
            float4v acc = __builtin_amdgcn_mfma_f32_16x16x32_f16(
                qh, bh, (float4v){0.f, 0.f, 0.f, 0.f}, 0, 0, 0);
            #pragma unroll
            for (int j = 0; j < 4; ++j) {
                float key = fmaf(-2.f, acc[j], sc);
                unsigned long long m = __ballot(key < Tth[j]);
                if (m) {
                    do {
                        int src = __ffsll(m) - 1;
                        float nk = readlane_f(key, src);
                        int sg = src >> 4;
                        float cut = readlane_f(selk[j], sg * 16 + 15);
                        if (nk < cut) {
                            float upk = dpp_shr1_f(selk[j]);
                            bool pme   = (nk < selk[j]) && ((lane >> 4) == sg);
                            bool pprev = (nk < upk) && ((lane & 15) != 0);
                            selk[j] = pme ? (pprev ? upk : nk) : selk[j];
                        }
                        m &= (m - 1);
                    } while (m);
                    Tth[j] = bcast15_f(selk[j]);
                }
            }
        }
        if (T + 1 < NTIL)
            stage_write(((T + 1) & 1) ? stream1 : stream0,
                        ((T + 1) & 1) ? sqs1 : sqs0);
        __syncthreads();
    }

    // pass-2 thresholds with rigorous fp16-error margin
    float T2[4];
    #pragma unroll
    for (int j = 0; j < 4; ++j) T2[j] = Tth[j] + EPS_MARGIN;

    // ================= PASS 2: rescan, collect survivors ==========
    if (tid < QPB) scnt[tid] = 0;
    stage_load(0);
    __syncthreads();          // scnt visible + stream buffers free
    stage_write(stream0, sqs0);
    __syncthreads();
    #pragma unroll 1
    for (int T = 0; T < NTIL; ++T) {
        stage_load((T + 1 < NTIL) ? T + 1 : T);
        const char*  cb = (T & 1) ? stream1 : stream0;
        const float* sv = (T & 1) ? sqs1 : sqs0;
        #pragma unroll
        for (int st = 0; st < 8; ++st) {
            half8 bh = *(const half8*)(cb + (size_t)(st * 16 + (lane & 15)) * CSTRIDE
                                          + (lane >> 4) * 16);
            float sc = sv[st * 16 + (lane & 15)];
            float4v acc = __builtin_amdgcn_mfma_f32_16x16x32_f16(
                qh, bh, (float4v){0.f, 0.f, 0.f, 0.f}, 0, 0, 0);
            #pragma unroll
            for (int j = 0; j < 4; ++j) {
                float key = fmaf(-2.f, acc[j], sc);
                unsigned long long m = __ballot(key < T2[j]);
                while (m) {
                    int src = __ffsll(m) - 1;
                    if (lane == src) {       // append in ascending candidate order
                        int qq = w * 16 + 4 * (src >> 4) + j;
                        int c  = scnt[qq];
                        if (c < SCAP) {
                            slist[qq * SCAP + c] = T * TILEC + st * 16 + (src & 15);
                            scnt[qq] = c + 1;
                        }
                    }
                    m &= (m - 1);
                }
            }
        }
        if (T + 1 < NTIL)
            stage_write(((T + 1) & 1) ? stream1 : stream0,
                        ((T + 1) & 1) ? sqs1 : sqs0);
        __syncthreads();
    }

    // ================= PASS 3: exact fp32 re-check of survivors ==========
    {
        int qq = tid & 63, sb = tid >> 6;
        int n = scnt[qq];
        const float4* xi4 = (const float4*)(xb + (size_t)(qbl + qq) * CCH);
        for (int s = sb; s < n; s += 4) {
            int jdx = slist[qq * SCAP + s];
            const float4* xj = (const float4*)(xb + (size_t)jdx * CCH);
            float a0 = 0.f, a1 = 0.f, a2 = 0.f, a3 = 0.f;
            #pragma unroll
            for (int k = 0; k < 8; ++k) {
                float4 cv = xj[k], qv = xi4[k];
                a0 = fmaf(cv.x, qv.x, a0); a1 = fmaf(cv.y, qv.y, a1);
                a2 = fmaf(cv.z, qv.z, a2); a3 = fmaf(cv.w, qv.w, a3);
            }
            float dot = (a0 + a1) + (a2 + a3);
            skeys[qq * SCAP + s] = fmaf(-2.f, dot, sqb[jdx]);
        }
    }
    __syncthreads();
    if (tid < QPB) {      // exact (key, idx) top-16; survivors are in ascending idx order
        int n = scnt[tid];
        float kd[KNN]; int ki[KNN];
        #pragma unroll
        for (int p = 0; p < KNN; ++p) { kd[p] = INF; ki[p] = 0x7fffffff; }
        for (int s = 0; s < n; ++s) {
            float ck = skeys[tid * SCAP + s];
            int   cj = slist[tid * SCAP + s];
            if (ck < kd[KNN - 1]) {          // strict <: earlier (lower) idx wins ties
                #pragma unroll
                for (int p = 0; p < KNN; ++p) {
                    bool sw = ck < kd[p];
                    float nk = sw ? ck : kd[p];
                    int   nj = sw ? cj : ki[p];
                    ck = sw ? kd[p] : ck;
                    cj = sw ? ki[p] : cj;
                    kd[p] = nk; ki[p] = nj;
                }
            }
        }
        #pragma unroll
        for (int r = 0; r < KNN; ++r) kn[tid * KNN + r] = ki[r];
    }
    __syncthreads();

    // ================= epilogue: gather + max-pool + MLP ==========
    {
        int q = tid >> 2, part = tid & 3;
        float4 m0 = make_float4(-INF, -INF, -INF, -INF);
        float4 m1 = m0;
        #pragma unroll
        for (int k = 0; k < KNN; ++k) {
            int j = kn[q * KNN + k];
            const float4* r = (const float4*)(xb + (size_t)j * CCH + part * 8);
            float4 v0 = r[0], v1 = r[1];
            m0.x = fmaxf(m0.x, v0.x); m0.y = fmaxf(m0.y, v0.y);
            m0.z = fmaxf(m0.z, v0.z); m0.w = fmaxf(m0.w, v0.w);
            m1.x = fmaxf(m1.x, v1.x); m1.y = fmaxf(m1.y, v1.y);
            m1.z = fmaxf(m1.z, v1.z); m1.w = fmaxf(m1.w, v1.w);
        }
        float* d = pl + q * 33 + part * 8;
        d[0] = m0.x; d[1] = m0.y; d[2] = m0.z; d[3] = m0.w;
        d[4] = m1.x; d[5] = m1.y; d[6] = m1.z; d[7] = m1.w;
    }
    __syncthreads();
    {
        int l = tid & 63, qg2 = tid >> 6;
        #pragma unroll 1
        for (int qq = qg2; qq < QPB; qq += 4) {
            float acc = bl[l];
            #pragma unroll
            for (int c = 0; c < CCH; ++c)
                acc = fmaf(pl[qq * 33 + c], Wl[c * LDIM + l], acc);
            hh[qq * 65 + l] = acc;
        }
    }
    __syncthreads();
    {
        int o = tid & 127, qh2 = tid >> 7;
        #pragma unroll 1
        for (int qq = qh2; qq < QPB; qq += 2) {
            float acc = bc[o];
            #pragma unroll
            for (int l = 0; l < LDIM; ++l)
                acc = fmaf(hh[qq * 65 + l], Wc[l * ODIM + o], acc);
            out[(size_t)(qb0 + qq) * ODIM + o] = fmaxf(acc, 0.f);
        }
    }
}

extern "C" void kernel_launch(void* const* d_in, const int* in_sizes, int n_in,
                              void* d_out, int out_size, void* d_ws, size_t ws_size,
                              hipStream_t stream) {
    const float* x  = (const float*)d_in[0];
    const float* Wl = (const float*)d_in[1];
    const float* bl = (const float*)d_in[2];
    const float* Wc = (const float*)d_in[3];
    const float* bc = (const float*)d_in[4];
    float* out = (float*)d_out;
    float* sqf = (float*)d_ws;                 // 32768 floats = 128 KB
    (void)in_sizes; (void)n_in; (void)out_size; (void)ws_size;

    hipLaunchKernelGGL(sq_kernel, dim3((4 * NPTS) / 256), dim3(256), 0, stream, x, sqf);
    hipLaunchKernelGGL(graph_layer_kernel, dim3(NBLK), dim3(256), 0, stream,
                       x, sqf, Wl, bl, Wc, bc, out);
}

// Round 9
// 307.874 us; speedup vs baseline: 11.5955x; 1.7083x over previous
//
#include <hip/hip_runtime.h>

#define NPTS   8192
#define CCH    32
#define LDIM   64
#define ODIM   128
#define KNN    16
#define QPB    64                  // queries per block (16 per wave = MFMA tile rows)
#define TILEC  128                 // candidates per LDS tile
#define NTIL   (NPTS / TILEC)      // 64
#define NBLK   ((4 * NPTS) / QPB)  // 512 blocks
#define SCAP   56                  // survivor capacity per query (analysis: worst ~40)
#define CSTRIDE 80                 // bytes per candidate row in LDS (32 fp16 + pad)
#define MARGIN 0.75f               // >= 2*eps bound for fp16 distance error

typedef _Float16 half8   __attribute__((ext_vector_type(8)));
typedef _Float16 half4v  __attribute__((ext_vector_type(4)));
typedef float    float4v __attribute__((ext_vector_type(4)));

// Prologue: squared norms of all 32768 points into d_ws (exact fp32).
__global__ void sq_kernel(const float* __restrict__ x, float* __restrict__ sqg) {
    int i = blockIdx.x * 256 + threadIdx.x;
    const float4* p = (const float4*)(x + (size_t)i * CCH);
    float s = 0.f;
    #pragma unroll
    for (int k = 0; k < 8; ++k) {
        float4 v = p[k];
        s += v.x * v.x + v.y * v.y + v.z * v.z + v.w * v.w;
    }
    sqg[i] = s;
}

// LDS layout (phase overlays):
//  scan:   s0 @0 (10240) | s1 @10240 (10240) | sq0 @20480 (512) | sq1 @20992 (512)
//          slist/t32 @21504 (14336) | scnt @35840 (256) | tq @36096 (256)
//  pass3:  skeys @0 (14336) | kn @14336 (4096)          (stream bufs dead)
//  epilog: pl @0 (8448) | hh @18432 (16640)             (skeys/slist dead)
#define LDS_BYTES 36352
#define OFF_S1   10240
#define OFF_SQ0  20480
#define OFF_SQ1  20992
#define OFF_SL   21504
#define OFF_SC   35840
#define OFF_TQ   36096
#define OFF_KN   14336
#define OFF_HH   18432

__global__ __launch_bounds__(256, 2)
void graph_layer_kernel(const float* __restrict__ x,
                        const float* __restrict__ sqg,
                        const float* __restrict__ Wl,
                        const float* __restrict__ bl,
                        const float* __restrict__ Wc,
                        const float* __restrict__ bc,
                        float* __restrict__ out)
{
    __shared__ __align__(16) char smem[LDS_BYTES];
    char*  s0    = smem;
    char*  s1    = smem + OFF_S1;
    float* sq0   = (float*)(smem + OFF_SQ0);
    float* sq1   = (float*)(smem + OFF_SQ1);
    int*   slist = (int*)(smem + OFF_SL);
    float* t32   = (float*)(smem + OFF_SL);    // overlay, consumed before slist writes
    int*   scnt  = (int*)(smem + OFF_SC);
    float* tq    = (float*)(smem + OFF_TQ);
    float* skeys = (float*)smem;               // pass-3 overlay
    int*   kn    = (int*)(smem + OFF_KN);
    float* pl    = (float*)smem;               // epilogue overlay
    float* hh    = (float*)(smem + OFF_HH);

    const int tid  = threadIdx.x;
    const int lane = tid & 63;
    const int w    = tid >> 6;
    const int col  = lane & 15;                // candidate column / A-frag row
    const int quad = lane >> 4;
    const float INF = __builtin_inff();

    const int qb0 = blockIdx.x * QPB;
    const int b   = qb0 >> 13;
    const int qbl = qb0 & (NPTS - 1);
    const float* xb  = x   + (size_t)(b << 13) * CCH;
    const float* sqb = sqg + (b << 13);

    // ---- A-fragment: wave's 16 queries in fp16; A[m=col][k=quad*8+j] ----
    half8 qh;
    {
        const float* qr = x + (size_t)(qb0 + w * 16 + col) * CCH + quad * 8;
        float4 f0 = *(const float4*)qr;
        float4 f1 = *(const float4*)(qr + 4);
        qh[0]=(_Float16)f0.x; qh[1]=(_Float16)f0.y; qh[2]=(_Float16)f0.z; qh[3]=(_Float16)f0.w;
        qh[4]=(_Float16)f1.x; qh[5]=(_Float16)f1.y; qh[6]=(_Float16)f1.z; qh[7]=(_Float16)f1.w;
    }

    float4 r0, r1, r2, r3; float sqv = 0.f;
    auto stage_load = [&](int T) {
        const float4* g = (const float4*)(xb + (size_t)T * TILEC * CCH);
        r0 = g[tid]; r1 = g[tid + 256]; r2 = g[tid + 512]; r3 = g[tid + 768];
        if (tid < TILEC) sqv = sqb[T * TILEC + tid];
    };
    auto stage_write = [&](char* buf, float* sqs) {
        auto wr = [&](int ch, float4 r) {
            int cd = ch >> 3, kq = ch & 7;
            half4v h;
            h[0]=(_Float16)r.x; h[1]=(_Float16)r.y; h[2]=(_Float16)r.z; h[3]=(_Float16)r.w;
            *(half4v*)(buf + cd * CSTRIDE + kq * 8) = h;
        };
        wr(tid, r0); wr(tid+256, r1); wr(tid+512, r2); wr(tid+768, r3);
        if (tid < TILEC) sqs[tid] = sqv;
    };

    // ================= PASS 1: branch-free per-lane top-2 per query ==========
    float m1[4] = {INF, INF, INF, INF};
    float m2[4] = {INF, INF, INF, INF};

    stage_load(0); stage_write(s0, sq0);
    __syncthreads();
    #pragma unroll 1
    for (int T = 0; T < NTIL; ++T) {
        if (T + 1 < NTIL) stage_load(T + 1);
        const char*  cb = (T & 1) ? s1 : s0;
        const float* sv = (T & 1) ? sq1 : sq0;
        #pragma unroll
        for (int st = 0; st < 8; ++st) {
            half8 bh = *(const half8*)(cb + (size_t)(st * 16 + col) * CSTRIDE + quad * 16);
            float sc = sv[st * 16 + col];
            float4v acc = __builtin_amdgcn_mfma_f32_16x16x32_f16(
                qh, bh, (float4v){0.f, 0.f, 0.f, 0.f}, 0, 0, 0);
            #pragma unroll
            for (int j = 0; j < 4; ++j) {
                float key = fmaf(-2.f, acc[j], sc);
                float lo = fminf(key, m1[j]);
                float hi = fmaxf(key, m1[j]);
                m1[j] = lo;
                m2[j] = fminf(m2[j], hi);
            }
        }
        if (T + 1 < NTIL) stage_write(((T + 1) & 1) ? s1 : s0,
                                      ((T + 1) & 1) ? sq1 : sq0);
        __syncthreads();
    }

    // ---- per-query threshold: 16th smallest of the 32-value union ----
    #pragma unroll
    for (int j = 0; j < 4; ++j) {
        int qq = w * 16 + quad * 4 + j;
        t32[qq * 32 + col * 2 + 0] = m1[j];
        t32[qq * 32 + col * 2 + 1] = m2[j];
    }
    __syncthreads();
    if (tid < QPB) {
        float kd[KNN];
        #pragma unroll
        for (int p = 0; p < KNN; ++p) kd[p] = INF;
        for (int i = 0; i < 32; ++i) {
            float ck = t32[tid * 32 + i];
            if (ck < kd[KNN - 1]) {
                #pragma unroll
                for (int p = 0; p < KNN; ++p) {
                    bool sw = ck < kd[p];
                    float nk = sw ? ck : kd[p];
                    ck = sw ? kd[p] : ck;
                    kd[p] = nk;
                }
            }
        }
        tq[tid] = kd[KNN - 1];
        scnt[tid] = 0;
    }
    __syncthreads();
    float T2[4];
    #pragma unroll
    for (int j = 0; j < 4; ++j) T2[j] = tq[w * 16 + quad * 4 + j] + MARGIN;

    // ================= PASS 2: rescan, atomic survivor append ==========
    stage_load(0); stage_write(s0, sq0);
    __syncthreads();
    #pragma unroll 1
    for (int T = 0; T < NTIL; ++T) {
        if (T + 1 < NTIL) stage_load(T + 1);
        const char*  cb = (T & 1) ? s1 : s0;
        const float* sv = (T & 1) ? sq1 : sq0;
        #pragma unroll
        for (int st = 0; st < 8; ++st) {
            half8 bh = *(const half8*)(cb + (size_t)(st * 16 + col) * CSTRIDE + quad * 16);
            float sc = sv[st * 16 + col];
            float4v acc = __builtin_amdgcn_mfma_f32_16x16x32_f16(
                qh, bh, (float4v){0.f, 0.f, 0.f, 0.f}, 0, 0, 0);
            #pragma unroll
            for (int j = 0; j < 4; ++j) {
                float key = fmaf(-2.f, acc[j], sc);
                if (key < T2[j]) {
                    int qq = w * 16 + quad * 4 + j;
                    int slot = atomicAdd(&scnt[qq], 1);
                    if (slot < SCAP)
                        slist[qq * SCAP + slot] = T * TILEC + st * 16 + col;
                }
            }
        }
        if (T + 1 < NTIL) stage_write(((T + 1) & 1) ? s1 : s0,
                                      ((T + 1) & 1) ? sq1 : sq0);
        __syncthreads();
    }

    // ================= PASS 3: exact fp32 re-check of survivors ==========
    {
        int qq = tid & 63, sb = tid >> 6;
        int n = scnt[qq]; if (n > SCAP) n = SCAP;
        const float4* xi4 = (const float4*)(xb + (size_t)(qbl + qq) * CCH);
        for (int s = sb; s < n; s += 4) {
            int jdx = slist[qq * SCAP + s];
            const float4* xj = (const float4*)(xb + (size_t)jdx * CCH);
            float a0 = 0.f, a1 = 0.f, a2 = 0.f, a3 = 0.f;
            #pragma unroll
            for (int k = 0; k < 8; ++k) {
                float4 cv = xj[k], qv = xi4[k];
                a0 = fmaf(cv.x, qv.x, a0); a1 = fmaf(cv.y, qv.y, a1);
                a2 = fmaf(cv.z, qv.z, a2); a3 = fmaf(cv.w, qv.w, a3);
            }
            float dot = (a0 + a1) + (a2 + a3);
            skeys[qq * SCAP + s] = fmaf(-2.f, dot, sqb[jdx]);
        }
    }
    __syncthreads();
    if (tid < QPB) {      // exact (key, idx) top-16; slist is UNORDERED -> full lex compare
        int n = scnt[tid]; if (n > SCAP) n = SCAP;
        float kd[KNN]; int ki[KNN];
        #pragma unroll
        for (int p = 0; p < KNN; ++p) { kd[p] = INF; ki[p] = 0x7fffffff; }
        for (int s = 0; s < n; ++s) {
            float ck = skeys[tid * SCAP + s];
            int   cj = slist[tid * SCAP + s];
            if (ck < kd[KNN-1] || (ck == kd[KNN-1] && cj < ki[KNN-1])) {
                #pragma unroll
                for (int p = 0; p < KNN; ++p) {
                    bool sw = (ck < kd[p]) || (ck == kd[p] && cj < ki[p]);
                    float nk = sw ? ck : kd[p];
                    int   nj = sw ? cj : ki[p];
                    ck = sw ? kd[p] : ck;
                    cj = sw ? ki[p] : cj;
                    kd[p] = nk; ki[p] = nj;
                }
            }
        }
        #pragma unroll
        for (int r = 0; r < KNN; ++r) kn[tid * KNN + r] = ki[r];
    }
    __syncthreads();

    // ================= epilogue: gather + max-pool + MLP ==========
    {
        int q = tid >> 2, part = tid & 3;
        float4 m0 = make_float4(-INF, -INF, -INF, -INF);
        float4 mm1 = m0;
        #pragma unroll
        for (int k = 0; k < KNN; ++k) {
            int j = kn[q * KNN + k];
            const float4* r = (const float4*)(xb + (size_t)j * CCH + part * 8);
            float4 v0 = r[0], v1 = r[1];
            m0.x = fmaxf(m0.x, v0.x); m0.y = fmaxf(m0.y, v0.y);
            m0.z = fmaxf(m0.z, v0.z); m0.w = fmaxf(m0.w, v0.w);
            mm1.x = fmaxf(mm1.x, v1.x); mm1.y = fmaxf(mm1.y, v1.y);
            mm1.z = fmaxf(mm1.z, v1.z); mm1.w = fmaxf(mm1.w, v1.w);
        }
        float* d = pl + q * 33 + part * 8;
        d[0] = m0.x; d[1] = m0.y; d[2] = m0.z; d[3] = m0.w;
        d[4] = mm1.x; d[5] = mm1.y; d[6] = mm1.z; d[7] = mm1.w;
    }
    __syncthreads();
    {
        int l = tid & 63, qg2 = tid >> 6;
        #pragma unroll 1
        for (int qq = qg2; qq < QPB; qq += 4) {
            float acc = bl[l];
            #pragma unroll
            for (int c = 0; c < CCH; ++c)
                acc = fmaf(pl[qq * 33 + c], Wl[c * LDIM + l], acc);
            hh[qq * 65 + l] = acc;
        }
    }
    __syncthreads();
    {
        int o = tid & 127, qh2 = tid >> 7;
        #pragma unroll 1
        for (int qq = qh2; qq < QPB; qq += 2) {
            float acc = bc[o];
            #pragma unroll
            for (int l = 0; l < LDIM; ++l)
                acc = fmaf(hh[qq * 65 + l], Wc[l * ODIM + o], acc);
            out[(size_t)(qb0 + qq) * ODIM + o] = fmaxf(acc, 0.f);
        }
    }
}

extern "C" void kernel_launch(void* const* d_in, const int* in_sizes, int n_in,
                              void* d_out, int out_size, void* d_ws, size_t ws_size,
                              hipStream_t stream) {
    const float* x  = (const float*)d_in[0];
    const float* Wl = (const float*)d_in[1];
    const float* bl = (const float*)d_in[2];
    const float* Wc = (const float*)d_in[3];
    const float* bc = (const float*)d_in[4];
    float* out = (float*)d_out;
    float* sqf = (float*)d_ws;                 // 32768 floats = 128 KB
    (void)in_sizes; (void)n_in; (void)out_size; (void)ws_size;

    hipLaunchKernelGGL(sq_kernel, dim3((4 * NPTS) / 256), dim3(256), 0, stream, x, sqf);
    hipLaunchKernelGGL(graph_layer_kernel, dim3(NBLK), dim3(256), 0, stream,
                       x, sqf, Wl, bl, Wc, bc, out);
}